// Round 11
// baseline (232.635 us; speedup 1.0000x reference)
//
#include <hip/hip_runtime.h>
#include <stdint.h>

// Per-row top-K magnitude masking, exact.
// x: (4096 rows, 8192 cols) fp32. K = 819. One 256-thread block per row, row
// held in registers (8 x uint4 / thread). Exact radix select on the 31-bit
// abs bit pattern: phase 1 = 11 bits (2048 bins); then ballot-compacted
// candidate list; phases 2/3 = 10+10 bits over the list only.
//
// R11 theory: the kernel is DS-PIPE-bound (~60% busy by hand count: 128
// atomic wave-ops x ~25-30 cyc + 256 mostly-empty predicated wave-ops for
// phases 2/3 + zero/combine) -- a pipe no counter we pull measures. Fixes:
//  1. Phase-1 8-way copy dilution with BANK-DISTINCT stride. R10's test was
//     confounded: S1=1032 (8 mod 32) put the 8 copies of a hot word on only
//     4 banks (bank-conflict counter rose 4.08M->4.58M, eating the
//     same-address gain). S1=1036 (12 mod 32, gcd(12,32)=4, 8 multiples
//     distinct) puts all 8 copies on distinct banks; uint4 alignment kept.
//  2. Phases 2/3 over a ballot-compacted list (R9's idea WITHOUT R9's
//     poison): per-wave segments, wave-uniform counts via ballot/popcount,
//     ZERO shared-counter atomics. ~200 list elements replace 2x128
//     predicated wave-ops over all 8192. Exact for any input: counts
//     tracked past capacity; uniform fallback to full-scan on overflow.

constexpr int NCOLS = 8192;
constexpr int TPB   = 256;
constexpr int V4    = NCOLS / 4;   // 2048 uint4 per row
constexpr int VPT   = V4 / TPB;    // 8 uint4 per thread

constexpr int W1  = 1024;          // phase-1 words per copy (2048 bins, u16-packed)
constexpr int S1  = 1036;          // copy stride: 1036%32=12 -> 8 copies hit
                                   // 8 distinct banks; divisible by 4 (uint4)
constexpr int C1  = 8;             // phase-1 copies: one per 8-lane group
constexpr int B2  = 1024;          // phase-2/3 bins (u32, single copy)
constexpr int S2  = B2 + 8;        // 1032 (fits inside hist region)
constexpr int HW  = C1 * S1;       // 8288 words = 33.2 KB

constexpr int CSEG = 256;          // candidate segment per wave (expect ~53)

struct Shared {
  uint32_t hist[HW];               // ph1: 8 copies; ph2/3: first S2 words
  uint32_t cand[4 * CSEG];         // 4 KB candidate keys (digit1 == d1)
  uint32_t segcnt[4];              // per-wave candidate counts (may exceed CSEG)
  uint32_t wavesum[4];
  uint32_t digit;
  uint32_t rem;
};

// Suffix-scan + winner pick shared by all phases. hb[] are this thread's bin
// counts over bins [tid*BPT, tid*BPT+BPT). S(b) = #candidates with digit >= b.
// Winner: S(b) >= rem && S(b+1) < rem (unique). Updates rem to rank in bin.
template <int BPT>
__device__ __forceinline__ uint32_t pick_winner(Shared& sh, const uint32_t (&hb)[BPT],
                                                uint32_t& rem, int tid, int lane, int wave) {
  uint32_t L = 0;
#pragma unroll
  for (int j = 0; j < BPT; ++j) L += hb[j];

  uint32_t suf = L;                        // wave inclusive suffix scan
#pragma unroll
  for (int off = 1; off < 64; off <<= 1) {
    uint32_t o = __shfl_down(suf, off, 64);
    suf += (lane + off < 64) ? o : 0u;
  }
  if (lane == 0) sh.wavesum[wave] = suf;   // wave total
  __syncthreads();
  uint32_t addw = 0;
#pragma unroll
  for (int w = 0; w < 4; ++w) addw += (w > wave) ? sh.wavesum[w] : 0u;
  suf += addw;  // suffix count starting at this thread's first bin

  uint32_t s = suf - L;                    // S at bin (tid+1)*BPT
#pragma unroll
  for (int j = BPT - 1; j >= 0; --j) {
    uint32_t snext = s;                    // S(bin+1)
    s += hb[j];                            // S(bin)
    if (s >= rem && snext < rem) {
      sh.digit = (uint32_t)(tid * BPT + j);
      sh.rem = rem - snext;
    }
  }
  __syncthreads();
  uint32_t d = sh.digit;
  rem = sh.rem;
  // No trailing barrier: the next stage's first barrier (after zeroing /
  // compaction) orders these reads before any write to digit/rem/wavesum.
  return d;
}

// Phase 1: 11-bit digit (bits 30..20), 2048 bins, u16-packed, 8 copies,
// copy = (tid>>3)&7 -> same-address RMW confined to 8 lanes AND the 8
// copies of any word sit on 8 distinct banks (stride 1036).
__device__ __forceinline__ uint32_t phase1(Shared& sh, const uint4 (&v)[VPT],
                                           uint32_t& rem, int tid, int lane, int wave) {
  uint4* hz = (uint4*)sh.hist;
  constexpr int ZW4 = (C1 * S1) / 4;       // 2072
  for (int i = tid; i < ZW4; i += TPB) hz[i] = make_uint4(0u, 0u, 0u, 0u);
  __syncthreads();

  uint32_t* h = &sh.hist[((tid >> 3) & 7) * S1];
#pragma unroll
  for (int i = 0; i < VPT; ++i) {
    uint32_t a[4] = {v[i].x, v[i].y, v[i].z, v[i].w};
#pragma unroll
    for (int j = 0; j < 4; ++j) {
      uint32_t d = (a[j] & 0x7fffffffu) >> 20;          // 11-bit digit
      atomicAdd(&h[d & (W1 - 1)], 1u << ((d >> 10) << 4));
    }
  }
  __syncthreads();

  // Combine: thread owns bins [tid*8, tid*8+8) (one halfword of 8 words).
  // Sum the 8 copies' words as packed u32 (half-sums <= 8192 < 2^16, no
  // carry), then extract this thread's half once.
  constexpr int BPT = 2048 / TPB;          // 8
  const int wbase = (tid & 127) * BPT;
  const int shift = (tid >> 7) << 4;
  uint32_t ws[BPT];
#pragma unroll
  for (int j = 0; j < BPT; ++j) ws[j] = 0;
#pragma unroll
  for (int c = 0; c < C1; ++c) {
    const uint4* hp = (const uint4*)&sh.hist[c * S1 + wbase];
    uint4 t0 = hp[0], t1 = hp[1];
    ws[0] += t0.x; ws[1] += t0.y; ws[2] += t0.z; ws[3] += t0.w;
    ws[4] += t1.x; ws[5] += t1.y; ws[6] += t1.z; ws[7] += t1.w;
  }
  uint32_t hb[BPT];
#pragma unroll
  for (int j = 0; j < BPT; ++j) hb[j] = (ws[j] >> shift) & 0xffffu;
  return pick_winner<BPT>(sh, hb, rem, tid, lane, wave);
}

// Phases 2/3 over the compacted list. Phase 2 (FILTER=false): digit = bits
// 19..10. Phase 3 (FILTER=true): digit = bits 9..0, keep digit2 == d2match.
template <bool FILTER>
__device__ __forceinline__ uint32_t phase_list(Shared& sh, int dshift,
                                               uint32_t d2match,
                                               uint32_t& rem, int tid, int lane, int wave) {
  uint4* hz = (uint4*)sh.hist;
  constexpr int ZW4 = S2 / 4;              // 258
  for (int i = tid; i < ZW4; i += TPB) hz[i] = make_uint4(0u, 0u, 0u, 0u);
  __syncthreads();

#pragma unroll
  for (int s = 0; s < 4; ++s) {
    const uint32_t n = sh.segcnt[s];       // uniform, <= CSEG (checked by caller)
    for (uint32_t p = tid; p < n; p += TPB) {
      uint32_t key = sh.cand[s * CSEG + p];
      if (!FILTER || (((key >> 10) & 1023u) == d2match))
        atomicAdd(&sh.hist[(key >> dshift) & (B2 - 1)], 1u);
    }
  }
  __syncthreads();

  constexpr int BPT = B2 / TPB;            // 4
  uint32_t hb[BPT];
  const uint4 t = *(const uint4*)&sh.hist[tid * BPT];
  hb[0] = t.x; hb[1] = t.y; hb[2] = t.z; hb[3] = t.w;
  return pick_winner<BPT>(sh, hb, rem, tid, lane, wave);
}

// Fallback full-scan phases 2/3 (only if a candidate segment overflows --
// impossible for this input, kept for exactness on any input).
__device__ __forceinline__ uint32_t phase23_full(Shared& sh, const uint4 (&v)[VPT],
                                                 int dshift, int cshift, uint32_t cprefix,
                                                 uint32_t& rem, int tid, int lane, int wave) {
  uint4* hz = (uint4*)sh.hist;
  constexpr int ZW4 = S2 / 4;
  for (int i = tid; i < ZW4; i += TPB) hz[i] = make_uint4(0u, 0u, 0u, 0u);
  __syncthreads();

#pragma unroll
  for (int i = 0; i < VPT; ++i) {
    uint32_t a[4] = {v[i].x, v[i].y, v[i].z, v[i].w};
#pragma unroll
    for (int j = 0; j < 4; ++j) {
      uint32_t key = a[j] & 0x7fffffffu;
      if ((key >> cshift) == cprefix)
        atomicAdd(&sh.hist[(key >> dshift) & (B2 - 1)], 1u);
    }
  }
  __syncthreads();

  constexpr int BPT = B2 / TPB;
  uint32_t hb[BPT];
  const uint4 t = *(const uint4*)&sh.hist[tid * BPT];
  hb[0] = t.x; hb[1] = t.y; hb[2] = t.z; hb[3] = t.w;
  return pick_winner<BPT>(sh, hb, rem, tid, lane, wave);
}

__global__ __launch_bounds__(TPB, 4) void topk_row_kernel(const float* __restrict__ x,
                                                          float* __restrict__ out,
                                                          int K) {
  __shared__ Shared sh;
  const int row  = blockIdx.x;
  const int tid  = threadIdx.x;
  const int lane = tid & 63;
  const int wave = tid >> 6;

  const uint4* xr = (const uint4*)(x) + (size_t)row * V4;
  uint4 v[VPT];
#pragma unroll
  for (int i = 0; i < VPT; ++i) v[i] = xr[tid + i * TPB];

  // Pin the row in the register file (forbids remat; AGPR parking proven
  // cheap in R4-R6). Zero instructions.
#pragma unroll
  for (int i = 0; i < VPT; ++i)
    asm volatile("" : "+v"(v[i].x), "+v"(v[i].y), "+v"(v[i].z), "+v"(v[i].w));

  uint32_t rem = (uint32_t)K;
  uint32_t d1 = phase1(sh, v, rem, tid, lane, wave);

  // Ballot-compaction of the d1 bin into per-wave segments. Wave-uniform
  // running count (no shared-counter atomics -- R9's poison). wcnt counts
  // ALL matches even past CSEG so the overflow test is exact.
  uint32_t wcnt = 0;
  const uint32_t segbase = (uint32_t)wave * CSEG;
#pragma unroll
  for (int i = 0; i < VPT; ++i) {
    uint32_t a[4] = {v[i].x, v[i].y, v[i].z, v[i].w};
#pragma unroll
    for (int j = 0; j < 4; ++j) {
      uint32_t key = a[j] & 0x7fffffffu;
      bool m = ((key >> 20) == d1);
      uint64_t mk = __ballot(m);
      uint32_t pos = wcnt + (uint32_t)__popcll(mk & ((1ull << lane) - 1ull));
      if (m && pos < (uint32_t)CSEG) sh.cand[segbase + pos] = key;
      wcnt += (uint32_t)__popcll(mk);
    }
  }
  if (lane == 0) sh.segcnt[wave] = wcnt;
  __syncthreads();

  bool ovf = false;
#pragma unroll
  for (int w = 0; w < 4; ++w) ovf |= (sh.segcnt[w] > (uint32_t)CSEG);

  uint32_t d2, d3;
  if (!ovf) {
    d2 = phase_list<false>(sh, 10, 0, rem, tid, lane, wave);
    d3 = phase_list<true>(sh, 0, d2, rem, tid, lane, wave);
  } else {
    d2 = phase23_full(sh, v, 10, 20, d1, rem, tid, lane, wave);
    d3 = phase23_full(sh, v, 0, 10, (d1 << 10) | d2, rem, tid, lane, wave);
  }

  const uint32_t thr = (d1 << 20) | (d2 << 10) | d3;  // exact K-th largest |x| bits

  uint4* outr = (uint4*)(out) + (size_t)row * V4;
#pragma unroll
  for (int i = 0; i < VPT; ++i) {
    uint4 o = v[i];
    o.x = ((o.x & 0x7fffffffu) >= thr) ? o.x : 0u;
    o.y = ((o.y & 0x7fffffffu) >= thr) ? o.y : 0u;
    o.z = ((o.z & 0x7fffffffu) >= thr) ? o.z : 0u;
    o.w = ((o.w & 0x7fffffffu) >= thr) ? o.w : 0u;
    outr[tid + i * TPB] = o;
  }
}

extern "C" void kernel_launch(void* const* d_in, const int* in_sizes, int n_in,
                              void* d_out, int out_size, void* d_ws, size_t ws_size,
                              hipStream_t stream) {
  (void)n_in; (void)out_size; (void)d_ws; (void)ws_size;
  const float* x = (const float*)d_in[0];
  float* out = (float*)d_out;
  const int rows = in_sizes[0] / NCOLS;
  const int K = (int)(0.1 * NCOLS + 0.5);  // round(819.2) = 819
  topk_row_kernel<<<rows, TPB, 0, stream>>>(x, out, K);
}